// Round 6
// baseline (160.069 us; speedup 1.0000x reference)
//
#include <hip/hip_runtime.h>
#include <hip/hip_bf16.h>

// Problem constants
constexpr int BATCH = 4;
constexpr int SEQ   = 4096;
constexpr int DIM   = 128;   // head size

// Q-block = 128 rows (4 waves x 32 rows). KV tiles = 64 keys.
// Split-KV: CHUNK KV-tiles (512 keys) per block.
constexpr int CHUNK       = 8;
constexpr int TASKS_PER_B = 144;                    // sum_{qt=0}^{31} ceil((2qt+2)/8)
constexpr int SLOT_F32    = 128 + 128 + 128 * 128;  // m[128], l[128], O[128][128]
constexpr size_t QKV_BYTES  = (size_t)3 * BATCH * SEQ * DIM * 2;
constexpr size_t PART_BYTES = (size_t)BATCH * TASKS_PER_B * SLOT_F32 * 4;

typedef __bf16 bf16x8 __attribute__((ext_vector_type(8)));
typedef float  f32x4  __attribute__((ext_vector_type(4)));

// ---------------------------------------------------------------------------
// Kernel 1: QKV projection. Grid (128, 3). 256 thr = 4 waves, 128 rows each.
// ---------------------------------------------------------------------------
__global__ __launch_bounds__(256) void qkv_proj(
    const float* __restrict__ x,
    const float* __restrict__ Wq, const float* __restrict__ Wk,
    const float* __restrict__ Wv,
    __bf16* __restrict__ q, __bf16* __restrict__ k, __bf16* __restrict__ v)
{
    __shared__ __align__(16) __bf16 Xl[128][136];
    __shared__ __align__(16) __bf16 Wt[128][136];   // W transposed: Wt[d][c]

    const int t    = threadIdx.x;
    const int lane = t & 63;
    const int w    = t >> 6;
    const int l15  = lane & 15;
    const int l4   = lane >> 4;
    const int rowblk = blockIdx.x * 128;
    const int m      = blockIdx.y;

    const float* W  = (m == 0) ? Wq : (m == 1) ? Wk : Wv;
    __bf16*      op = (m == 0) ? q  : (m == 1) ? k  : v;

    #pragma unroll
    for (int i = 0; i < 16; ++i) {
        int idx = i * 256 + t;
        int r   = idx >> 5;
        int c4  = (idx & 31) << 2;
        float4 f = *(const float4*)(x + (size_t)(rowblk + r) * DIM + c4);
        __bf16* dst = &Xl[r][c4];
        dst[0] = (__bf16)f.x; dst[1] = (__bf16)f.y;
        dst[2] = (__bf16)f.z; dst[3] = (__bf16)f.w;
    }
    #pragma unroll
    for (int i = 0; i < 16; ++i) {
        int idx = i * 256 + t;
        int r   = idx >> 5;
        int c4  = (idx & 31) << 2;
        float4 f = *(const float4*)(W + (size_t)r * DIM + c4);
        Wt[c4 + 0][r] = (__bf16)f.x;
        Wt[c4 + 1][r] = (__bf16)f.y;
        Wt[c4 + 2][r] = (__bf16)f.z;
        Wt[c4 + 3][r] = (__bf16)f.w;
    }
    __syncthreads();

    f32x4 acc[2][8];
    #pragma unroll
    for (int a = 0; a < 2; ++a)
        #pragma unroll
        for (int cf = 0; cf < 8; ++cf) acc[a][cf] = (f32x4){0.f, 0.f, 0.f, 0.f};

    #pragma unroll
    for (int kc = 0; kc < 4; ++kc) {
        bf16x8 af0 = *(const bf16x8*)&Xl[w * 32 +      l15][kc * 32 + l4 * 8];
        bf16x8 af1 = *(const bf16x8*)&Xl[w * 32 + 16 + l15][kc * 32 + l4 * 8];
        #pragma unroll
        for (int cf = 0; cf < 8; ++cf) {
            bf16x8 bfr = *(const bf16x8*)&Wt[cf * 16 + l15][kc * 32 + l4 * 8];
            acc[0][cf] = __builtin_amdgcn_mfma_f32_16x16x32_bf16(af0, bfr, acc[0][cf], 0, 0, 0);
            acc[1][cf] = __builtin_amdgcn_mfma_f32_16x16x32_bf16(af1, bfr, acc[1][cf], 0, 0, 0);
        }
    }

    #pragma unroll
    for (int a = 0; a < 2; ++a)
        #pragma unroll
        for (int cf = 0; cf < 8; ++cf)
            #pragma unroll
            for (int r2 = 0; r2 < 4; ++r2) {
                int row = rowblk + w * 32 + a * 16 + l4 * 4 + r2;
                int col = cf * 16 + l15;
                op[(size_t)row * DIM + col] = (__bf16)acc[a][cf][r2];
            }
}

// ---------------------------------------------------------------------------
// Kernel 2: causal flash attention, split-KV, 128 Q-rows/block (32/wave).
// Per-tile code paths are R2's verified ones: K LDS-staged, V transposed into
// Vt[128][72] with XOR key-chunk swizzle, P via per-wave LDS round-trip.
// K and V reg-prefetched during compute (T14), written to LDS at tile top.
// ---------------------------------------------------------------------------
template <bool SPLIT>
__global__ __launch_bounds__(256) void attn(
    const __bf16* __restrict__ q, const __bf16* __restrict__ k,
    const __bf16* __restrict__ v, float* __restrict__ out,
    float* __restrict__ part)
{
    __shared__ __align__(16) __bf16 Kl[64][136];
    __shared__ __align__(16) __bf16 Vt[128][72];
    __shared__ __align__(16) __bf16 Pl[4][32][72];

    const int t    = threadIdx.x;
    const int lane = t & 63;
    const int w    = t >> 6;
    const int l15  = lane & 15;
    const int l4   = lane >> 4;
    const int b    = blockIdx.y;

    int qt, chunk, nch, slot = 0;
    if (SPLIT) {
        int j = blockIdx.x;                 // 0..143
        int g = 0;
        while (g < 7 && j >= 2 * (g + 1) * (g + 2)) ++g;
        int r = j - 2 * g * (g + 1);
        nch   = g + 1;
        qt    = 4 * g + r / nch;
        chunk = r - (r / nch) * nch;
        slot  = b * TASKS_PER_B + j;
    } else {
        qt = blockIdx.x; chunk = 0; nch = 1;
    }
    const int qb0 = qt * 128;
    const int jt0 = chunk * CHUNK;
    const int jtE = SPLIT ? min(jt0 + CHUNK, 2 * qt + 2) : 2 * qt + 2;
    const size_t base = (size_t)b * SEQ * DIM;

    // staging geometry
    const int rr  = t >> 4;        // 0..15  (K rows)
    const int cc0 = (t & 15) * 8;  // K d-base
    const int vp  = t >> 5;        // 0..7   (V key pair)
    const int vd  = (t & 31) * 4;  // V d-base

    // Q fragments: qf[a][dc], rows qb0 + w*32 + a*16 + l15
    bf16x8 qf[2][4];
    #pragma unroll
    for (int a = 0; a < 2; ++a) {
        const __bf16* qrow = q + base + (size_t)(qb0 + w * 32 + a * 16 + l15) * DIM;
        #pragma unroll
        for (int dc = 0; dc < 4; ++dc)
            qf[a][dc] = *(const bf16x8*)(qrow + dc * 32 + l4 * 8);
    }

    f32x4 o[2][8];
    #pragma unroll
    for (int a = 0; a < 2; ++a)
        #pragma unroll
        for (int i = 0; i < 8; ++i) o[a][i] = (f32x4){0.f, 0.f, 0.f, 0.f};
    float mr[2][4], lr[2][4];
    #pragma unroll
    for (int a = 0; a < 2; ++a)
        #pragma unroll
        for (int r = 0; r < 4; ++r) { mr[a][r] = -INFINITY; lr[a][r] = 0.f; }

    // logits scaled by (1/sqrt(128))*log2(e); softmax in exp2 domain
    const float kScaleLog2e = 0.1275174454976458f;

    // ---- prologue: first K tile and V tile into regs ----
    int4 kreg[4];
    ushort4 va[4], vb[4];
    {
        const __bf16* kg = k + base + (size_t)jt0 * 64 * DIM;
        const __bf16* vg = v + base + (size_t)jt0 * 64 * DIM;
        #pragma unroll
        for (int i = 0; i < 4; ++i) {
            kreg[i] = *(const int4*)(kg + (size_t)(i * 16 + rr) * DIM + cc0);
            int k0 = i * 16 + 2 * vp;
            va[i] = *(const ushort4*)(vg + (size_t)k0 * DIM + vd);
            vb[i] = *(const ushort4*)(vg + (size_t)(k0 + 1) * DIM + vd);
        }
    }

    for (int jt = jt0; jt < jtE; ++jt) {
        __syncthreads();   // all waves done reading Kl/Vt of previous tile

        // ---- stage K (regs->LDS) and V (regs->Vt transposed+swizzled) ----
        #pragma unroll
        for (int i = 0; i < 4; ++i) {
            *(int4*)&Kl[i * 16 + rr][cc0] = kreg[i];
            int k0 = i * 16 + 2 * vp;
            #pragma unroll
            for (int e = 0; e < 4; ++e) {
                int cc  = vd + e;                                  // d index
                int col = (((k0 >> 3) ^ ((cc >> 3) & 7)) << 3) | (k0 & 7);
                ushort2 pr;
                pr.x = (&va[i].x)[e];
                pr.y = (&vb[i].x)[e];
                *(ushort2*)&Vt[cc][col] = pr;
            }
        }
        __syncthreads();   // Kl/Vt visible

        // ---- S = Q K^T (both row-fragments share each kf read) ----
        f32x4 s[2][4];
        #pragma unroll
        for (int kc = 0; kc < 4; ++kc) {
            f32x4 acc0 = (f32x4){0.f, 0.f, 0.f, 0.f};
            f32x4 acc1 = (f32x4){0.f, 0.f, 0.f, 0.f};
            #pragma unroll
            for (int dc = 0; dc < 4; ++dc) {
                bf16x8 kf = *(const bf16x8*)&Kl[kc * 16 + l15][dc * 32 + l4 * 8];
                acc0 = __builtin_amdgcn_mfma_f32_16x16x32_bf16(qf[0][dc], kf, acc0, 0, 0, 0);
                acc1 = __builtin_amdgcn_mfma_f32_16x16x32_bf16(qf[1][dc], kf, acc1, 0, 0, 0);
            }
            s[0][kc] = acc0;
            s[1][kc] = acc1;
        }

        // ---- prefetch next tile's K/V into regs (hides under softmax+PV) ----
        if (jt + 1 < jtE) {
            const __bf16* kg = k + base + (size_t)(jt + 1) * 64 * DIM;
            const __bf16* vg = v + base + (size_t)(jt + 1) * 64 * DIM;
            #pragma unroll
            for (int i = 0; i < 4; ++i) {
                kreg[i] = *(const int4*)(kg + (size_t)(i * 16 + rr) * DIM + cc0);
                int k0 = i * 16 + 2 * vp;
                va[i] = *(const ushort4*)(vg + (size_t)k0 * DIM + vd);
                vb[i] = *(const ushort4*)(vg + (size_t)(k0 + 1) * DIM + vd);
            }
        }

        // ---- scale(+log2e) + causal mask + online softmax (exp2 domain) ----
        const bool diag = (jt >= 2 * qt);   // last two tiles straddle diagonal
        #pragma unroll
        for (int a = 0; a < 2; ++a) {
            float rowmax[4];
            #pragma unroll
            for (int r = 0; r < 4; ++r) rowmax[r] = -INFINITY;
            #pragma unroll
            for (int kc = 0; kc < 4; ++kc) {
                int key = jt * 64 + kc * 16 + l15;
                #pragma unroll
                for (int r = 0; r < 4; ++r) {
                    float sv = s[a][kc][r] * kScaleLog2e;
                    if (diag) {
                        int qrow = qb0 + w * 32 + a * 16 + l4 * 4 + r;
                        if (key > qrow) sv = -INFINITY;
                    }
                    s[a][kc][r] = sv;
                    rowmax[r] = fmaxf(rowmax[r], sv);
                }
            }
            #pragma unroll
            for (int r = 0; r < 4; ++r) {
                float x2 = rowmax[r];
                x2 = fmaxf(x2, __shfl_xor(x2, 1));
                x2 = fmaxf(x2, __shfl_xor(x2, 2));
                x2 = fmaxf(x2, __shfl_xor(x2, 4));
                x2 = fmaxf(x2, __shfl_xor(x2, 8));
                rowmax[r] = x2;
            }
            float alpha[4];
            #pragma unroll
            for (int r = 0; r < 4; ++r) {
                float mnew = fmaxf(mr[a][r], rowmax[r]);
                alpha[r]   = exp2f(mr[a][r] - mnew);
                mr[a][r]   = mnew;
            }
            float rowsum[4] = {0.f, 0.f, 0.f, 0.f};
            #pragma unroll
            for (int kc = 0; kc < 4; ++kc)
                #pragma unroll
                for (int r = 0; r < 4; ++r) {
                    float p = exp2f(s[a][kc][r] - mr[a][r]);
                    s[a][kc][r] = p;
                    rowsum[r] += p;
                }
            #pragma unroll
            for (int r = 0; r < 4; ++r) {
                float x2 = rowsum[r];
                x2 += __shfl_xor(x2, 1);
                x2 += __shfl_xor(x2, 2);
                x2 += __shfl_xor(x2, 4);
                x2 += __shfl_xor(x2, 8);
                lr[a][r] = lr[a][r] * alpha[r] + x2;
            }
            #pragma unroll
            for (int df = 0; df < 8; ++df)
                #pragma unroll
                for (int r = 0; r < 4; ++r) o[a][df][r] *= alpha[r];

            // P -> bf16 A-fragment layout via per-wave LDS
            #pragma unroll
            for (int kc = 0; kc < 4; ++kc)
                #pragma unroll
                for (int r = 0; r < 4; ++r)
                    Pl[w][a * 16 + l4 * 4 + r][kc * 16 + l15] = (__bf16)s[a][kc][r];
        }

        // ---- O += P V (vf reads shared across both row-fragments) ----
        #pragma unroll
        for (int pc = 0; pc < 2; ++pc) {
            bf16x8 pa0 = *(const bf16x8*)&Pl[w][     l15][pc * 32 + l4 * 8];
            bf16x8 pa1 = *(const bf16x8*)&Pl[w][16 + l15][pc * 32 + l4 * 8];
            #pragma unroll
            for (int df = 0; df < 8; ++df) {
                int cc  = df * 16 + l15;
                int kch = (pc * 4 + l4) ^ ((cc >> 3) & 7);
                bf16x8 vf = *(const bf16x8*)&Vt[cc][kch * 8];
                o[0][df] = __builtin_amdgcn_mfma_f32_16x16x32_bf16(pa0, vf, o[0][df], 0, 0, 0);
                o[1][df] = __builtin_amdgcn_mfma_f32_16x16x32_bf16(pa1, vf, o[1][df], 0, 0, 0);
            }
        }
    }

    if (!SPLIT || nch == 1) {
        float* op = out + base;
        #pragma unroll
        for (int a = 0; a < 2; ++a) {
            float inv[4];
            #pragma unroll
            for (int r = 0; r < 4; ++r) inv[r] = 1.0f / lr[a][r];
            #pragma unroll
            for (int df = 0; df < 8; ++df)
                #pragma unroll
                for (int r = 0; r < 4; ++r) {
                    int row = qb0 + w * 32 + a * 16 + l4 * 4 + r;
                    op[(size_t)row * DIM + df * 16 + l15] = o[a][df][r] * inv[r];
                }
        }
    } else {
        float* sp = part + (size_t)slot * SLOT_F32;
        #pragma unroll
        for (int a = 0; a < 2; ++a) {
            #pragma unroll
            for (int r = 0; r < 4; ++r) {
                int rl = w * 32 + a * 16 + l4 * 4 + r;
                if (l15 == 0) { sp[rl] = mr[a][r]; sp[128 + rl] = lr[a][r]; }
            }
            #pragma unroll
            for (int df = 0; df < 8; ++df)
                #pragma unroll
                for (int r = 0; r < 4; ++r) {
                    int rl = w * 32 + a * 16 + l4 * 4 + r;
                    sp[256 + (size_t)rl * 128 + df * 16 + l15] = o[a][df][r];
                }
        }
    }
}

// ---------------------------------------------------------------------------
// Kernel 3: combine partials for qt >= 4 (nch >= 2). Grid (28, B), 256 thr.
// Thread t: row = t>>1 (0..127), cols [(t&1)*64, +64).
// m/l are in the exp2 domain -- weights use exp2f.
// ---------------------------------------------------------------------------
__global__ __launch_bounds__(256) void combine(
    const float* __restrict__ part, float* __restrict__ out)
{
    const int qt  = blockIdx.x + 4;
    const int b   = blockIdx.y;
    const int g   = qt >> 2;
    const int nch = g + 1;
    const int slot0 = b * TASKS_PER_B + 2 * g * (g + 1) + (qt & 3) * nch;

    const int t   = threadIdx.x;
    const int row = t >> 1;
    const int c0  = (t & 1) * 64;

    float M = -INFINITY;
    for (int c = 0; c < nch; ++c)
        M = fmaxf(M, part[(size_t)(slot0 + c) * SLOT_F32 + row]);
    float L = 0.f;
    for (int c = 0; c < nch; ++c) {
        const float* sp = part + (size_t)(slot0 + c) * SLOT_F32;
        L += sp[128 + row] * exp2f(sp[row] - M);
    }

    float4 acc[16];
    #pragma unroll
    for (int i = 0; i < 16; ++i) acc[i] = (float4){0.f, 0.f, 0.f, 0.f};
    for (int c = 0; c < nch; ++c) {
        const float* sp = part + (size_t)(slot0 + c) * SLOT_F32;
        float wgt = exp2f(sp[row] - M);
        const float* op = sp + 256 + (size_t)row * 128 + c0;
        #pragma unroll
        for (int i = 0; i < 16; ++i) {
            float4 f = *(const float4*)(op + i * 4);
            acc[i].x += wgt * f.x; acc[i].y += wgt * f.y;
            acc[i].z += wgt * f.z; acc[i].w += wgt * f.w;
        }
    }
    float invL = 1.0f / L;
    float* o = out + ((size_t)b * SEQ + (size_t)qt * 128 + row) * DIM + c0;
    #pragma unroll
    for (int i = 0; i < 16; ++i) {
        float4 f;
        f.x = acc[i].x * invL; f.y = acc[i].y * invL;
        f.z = acc[i].z * invL; f.w = acc[i].w * invL;
        *(float4*)(o + i * 4) = f;
    }
}

// ---------------------------------------------------------------------------
extern "C" void kernel_launch(void* const* d_in, const int* in_sizes, int n_in,
                              void* d_out, int out_size, void* d_ws, size_t ws_size,
                              hipStream_t stream) {
    const float* x  = (const float*)d_in[0];
    const float* Wq = (const float*)d_in[1];
    const float* Wk = (const float*)d_in[2];
    const float* Wv = (const float*)d_in[3];
    float* out = (float*)d_out;

    __bf16* qw = (__bf16*)d_ws;
    __bf16* kw = qw + (size_t)BATCH * SEQ * DIM;
    __bf16* vw = kw + (size_t)BATCH * SEQ * DIM;
    float*  part = (float*)((char*)d_ws + QKV_BYTES);

    qkv_proj<<<dim3(BATCH * SEQ / 128, 3), 256, 0, stream>>>(x, Wq, Wk, Wv, qw, kw, vw);

    if (ws_size >= QKV_BYTES + PART_BYTES) {
        attn<true><<<dim3(TASKS_PER_B, BATCH), 256, 0, stream>>>(qw, kw, vw, out, part);
        combine<<<dim3(28, BATCH), 256, 0, stream>>>(part, out);
    } else {
        attn<false><<<dim3(SEQ / 128, BATCH), 256, 0, stream>>>(qw, kw, vw, out, part);
    }
}

// Round 7
// 118.787 us; speedup vs baseline: 1.3475x; 1.3475x over previous
//
#include <hip/hip_runtime.h>
#include <hip/hip_bf16.h>

// Problem constants
constexpr int BATCH = 4;
constexpr int SEQ   = 4096;
constexpr int DIM   = 128;   // head size

// Split-KV config: KV tiles are 64 keys; CHUNK tiles per split block.
constexpr int CHUNK       = 8;                    // 512 keys per block
constexpr int TASKS_PER_B = 288;                  // sum_qt ceil((qt+1)/8)
constexpr int SLOT_F32    = 64 + 64 + 64 * 128;   // m[64], l[64], O[64][128]
constexpr size_t QKV_BYTES  = (size_t)3 * BATCH * SEQ * DIM * 2;
constexpr size_t PART_BYTES = (size_t)BATCH * TASKS_PER_B * SLOT_F32 * 4;

typedef __bf16 bf16x8 __attribute__((ext_vector_type(8)));
typedef __bf16 bf16x4 __attribute__((ext_vector_type(4)));
typedef float  f32x4  __attribute__((ext_vector_type(4)));

// ---------------------------------------------------------------------------
// Kernel 1: QKV projection. Grid (128, 3). 256 thr = 4 waves, 128 rows each.
// ---------------------------------------------------------------------------
__global__ __launch_bounds__(256) void qkv_proj(
    const float* __restrict__ x,
    const float* __restrict__ Wq, const float* __restrict__ Wk,
    const float* __restrict__ Wv,
    __bf16* __restrict__ q, __bf16* __restrict__ k, __bf16* __restrict__ v)
{
    __shared__ __align__(16) __bf16 Xl[128][136];
    __shared__ __align__(16) __bf16 Wt[128][136];   // W transposed: Wt[d][c]

    const int t    = threadIdx.x;
    const int lane = t & 63;
    const int w    = t >> 6;
    const int l15  = lane & 15;
    const int l4   = lane >> 4;
    const int rowblk = blockIdx.x * 128;
    const int m      = blockIdx.y;

    const float* W  = (m == 0) ? Wq : (m == 1) ? Wk : Wv;
    __bf16*      op = (m == 0) ? q  : (m == 1) ? k  : v;

    #pragma unroll
    for (int i = 0; i < 16; ++i) {
        int idx = i * 256 + t;
        int r   = idx >> 5;
        int c4  = (idx & 31) << 2;
        float4 f = *(const float4*)(x + (size_t)(rowblk + r) * DIM + c4);
        __bf16* dst = &Xl[r][c4];
        dst[0] = (__bf16)f.x; dst[1] = (__bf16)f.y;
        dst[2] = (__bf16)f.z; dst[3] = (__bf16)f.w;
    }
    #pragma unroll
    for (int i = 0; i < 16; ++i) {
        int idx = i * 256 + t;
        int r   = idx >> 5;
        int c4  = (idx & 31) << 2;
        float4 f = *(const float4*)(W + (size_t)r * DIM + c4);
        Wt[c4 + 0][r] = (__bf16)f.x;
        Wt[c4 + 1][r] = (__bf16)f.y;
        Wt[c4 + 2][r] = (__bf16)f.z;
        Wt[c4 + 3][r] = (__bf16)f.w;
    }
    __syncthreads();

    f32x4 acc[2][8];
    #pragma unroll
    for (int a = 0; a < 2; ++a)
        #pragma unroll
        for (int cf = 0; cf < 8; ++cf) acc[a][cf] = (f32x4){0.f, 0.f, 0.f, 0.f};

    #pragma unroll
    for (int kc = 0; kc < 4; ++kc) {
        bf16x8 af0 = *(const bf16x8*)&Xl[w * 32 +      l15][kc * 32 + l4 * 8];
        bf16x8 af1 = *(const bf16x8*)&Xl[w * 32 + 16 + l15][kc * 32 + l4 * 8];
        #pragma unroll
        for (int cf = 0; cf < 8; ++cf) {
            bf16x8 bfr = *(const bf16x8*)&Wt[cf * 16 + l15][kc * 32 + l4 * 8];
            acc[0][cf] = __builtin_amdgcn_mfma_f32_16x16x32_bf16(af0, bfr, acc[0][cf], 0, 0, 0);
            acc[1][cf] = __builtin_amdgcn_mfma_f32_16x16x32_bf16(af1, bfr, acc[1][cf], 0, 0, 0);
        }
    }

    #pragma unroll
    for (int a = 0; a < 2; ++a)
        #pragma unroll
        for (int cf = 0; cf < 8; ++cf)
            #pragma unroll
            for (int r2 = 0; r2 < 4; ++r2) {
                int row = rowblk + w * 32 + a * 16 + l4 * 4 + r2;
                int col = cf * 16 + l15;
                op[(size_t)row * DIM + col] = (__bf16)acc[a][cf][r2];
            }
}

// ---------------------------------------------------------------------------
// Kernel 2: causal flash attention, split-KV, swapped-operand QK^T.
// mfma(A=K-frag, B=Q-frag) -> S^T: lane holds S[q=l15][key=kc*16+l4*4+r].
// Softmax is lane-local (15-op trees + shfl_xor 16/32); P emerges transposed
// and is written as 4x ds_write_b64. PV path identical to proven R2.
// K/V reg-prefetched during compute (T14); V staged pair-packed (R5-proven).
// ---------------------------------------------------------------------------
template <bool SPLIT>
__global__ __launch_bounds__(256) void attn(
    const __bf16* __restrict__ q, const __bf16* __restrict__ k,
    const __bf16* __restrict__ v, float* __restrict__ out,
    float* __restrict__ part)
{
    __shared__ __align__(16) __bf16 Kl[64][136];
    __shared__ __align__(16) __bf16 Vt[128][72];
    __shared__ __align__(16) __bf16 Pl[4][16][72];

    const int t    = threadIdx.x;
    const int lane = t & 63;
    const int w    = t >> 6;
    const int l15  = lane & 15;
    const int l4   = lane >> 4;
    const int b    = blockIdx.y;

    int qt, chunk, nch, slot = 0;
    if (SPLIT) {
        int j = blockIdx.x;                 // 0..287
        int g = 0;
        while (g < 7 && j >= 4 * (g + 1) * (g + 2)) ++g;
        int r = j - 4 * g * (g + 1);
        nch   = g + 1;
        qt    = 8 * g + r / nch;
        chunk = r - (r / nch) * nch;
        slot  = b * TASKS_PER_B + j;
    } else {
        qt = blockIdx.x; chunk = 0; nch = 1;
    }
    const int qb0 = qt * 64;
    const int jt0 = chunk * CHUNK;
    const int jtE = SPLIT ? min(jt0 + CHUNK, qt + 1) : qt + 1;
    const size_t base = (size_t)b * SEQ * DIM;

    // staging geometry
    const int rr  = t >> 4;        // 0..15  (K rows)
    const int cc0 = (t & 15) * 8;  // K d-base
    const int vp  = t >> 5;        // 0..7   (V key pair)
    const int vd  = (t & 31) * 4;  // V d-base

    // Q fragments (used as MFMA B-operand: col m = l15, k = 32*dc + l4*8 + j)
    bf16x8 qf[4];
    {
        const __bf16* qrow = q + base + (size_t)(qb0 + w * 16 + l15) * DIM;
        #pragma unroll
        for (int dc = 0; dc < 4; ++dc)
            qf[dc] = *(const bf16x8*)(qrow + dc * 32 + l4 * 8);
    }

    f32x4 o[8];
    #pragma unroll
    for (int i = 0; i < 8; ++i) o[i] = (f32x4){0.f, 0.f, 0.f, 0.f};
    // per-lane running max / sum for query q = qb0 + w*16 + l15
    float mr = -INFINITY, lr = 0.f;

    // logits scaled by (1/sqrt(128))*log2(e); softmax in exp2 domain
    const float kScaleLog2e = 0.1275174454976458f;

    // ---- prologue: first K and V tiles into regs ----
    int4 kreg[4];
    ushort4 va[4], vb[4];
    {
        const __bf16* kg = k + base + (size_t)jt0 * 64 * DIM;
        const __bf16* vg = v + base + (size_t)jt0 * 64 * DIM;
        #pragma unroll
        for (int i = 0; i < 4; ++i) {
            kreg[i] = *(const int4*)(kg + (size_t)(i * 16 + rr) * DIM + cc0);
            int k0 = i * 16 + 2 * vp;
            va[i] = *(const ushort4*)(vg + (size_t)k0 * DIM + vd);
            vb[i] = *(const ushort4*)(vg + (size_t)(k0 + 1) * DIM + vd);
        }
    }

    for (int jt = jt0; jt < jtE; ++jt) {
        __syncthreads();   // all waves done reading Kl/Vt of previous tile

        // ---- stage K (regs->LDS) and V (regs->Vt transposed+swizzled) ----
        #pragma unroll
        for (int i = 0; i < 4; ++i) {
            *(int4*)&Kl[i * 16 + rr][cc0] = kreg[i];
            int k0 = i * 16 + 2 * vp;
            #pragma unroll
            for (int e = 0; e < 4; ++e) {
                int cc  = vd + e;                                  // d index
                int col = (((k0 >> 3) ^ ((cc >> 3) & 7)) << 3) | (k0 & 7);
                ushort2 pr;
                pr.x = (&va[i].x)[e];
                pr.y = (&vb[i].x)[e];
                *(ushort2*)&Vt[cc][col] = pr;
            }
        }
        __syncthreads();   // Kl/Vt visible

        // ---- S^T = K Q^T : lane gets S[q=l15][key = kc*16 + l4*4 + r] ----
        f32x4 s[4];
        #pragma unroll
        for (int kc = 0; kc < 4; ++kc) {
            f32x4 acc = (f32x4){0.f, 0.f, 0.f, 0.f};
            #pragma unroll
            for (int dc = 0; dc < 4; ++dc) {
                bf16x8 kf = *(const bf16x8*)&Kl[kc * 16 + l15][dc * 32 + l4 * 8];
                acc = __builtin_amdgcn_mfma_f32_16x16x32_bf16(kf, qf[dc], acc, 0, 0, 0);
            }
            s[kc] = acc;
        }

        // ---- prefetch next tile's K/V into regs (hides under softmax+PV) ----
        if (jt + 1 < jtE) {
            const __bf16* kg = k + base + (size_t)(jt + 1) * 64 * DIM;
            const __bf16* vg = v + base + (size_t)(jt + 1) * 64 * DIM;
            #pragma unroll
            for (int i = 0; i < 4; ++i) {
                kreg[i] = *(const int4*)(kg + (size_t)(i * 16 + rr) * DIM + cc0);
                int k0 = i * 16 + 2 * vp;
                va[i] = *(const ushort4*)(vg + (size_t)k0 * DIM + vd);
                vb[i] = *(const ushort4*)(vg + (size_t)(k0 + 1) * DIM + vd);
            }
        }

        // ---- scale(+log2e) + causal mask + lane-local online softmax ----
        const bool diag = (jt == qt);
        const int  qrow = qb0 + w * 16 + l15;      // this lane's query row
        float pmax = -INFINITY;
        #pragma unroll
        for (int kc = 0; kc < 4; ++kc) {
            #pragma unroll
            for (int r = 0; r < 4; ++r) {
                float sv = s[kc][r] * kScaleLog2e;
                if (diag) {
                    int key = jt * 64 + kc * 16 + l4 * 4 + r;
                    if (key > qrow) sv = -INFINITY;
                }
                s[kc][r] = sv;
                pmax = fmaxf(pmax, sv);
            }
        }
        pmax = fmaxf(pmax, __shfl_xor(pmax, 16));
        pmax = fmaxf(pmax, __shfl_xor(pmax, 32));

        float mnew  = fmaxf(mr, pmax);
        float alpha = exp2f(mr - mnew);
        mr = mnew;

        float psum = 0.f;
        #pragma unroll
        for (int kc = 0; kc < 4; ++kc)
            #pragma unroll
            for (int r = 0; r < 4; ++r) {
                float p = exp2f(s[kc][r] - mr);
                s[kc][r] = p;
                psum += p;
            }
        psum += __shfl_xor(psum, 16);
        psum += __shfl_xor(psum, 32);
        lr = lr * alpha + psum;

        // rescale O: alpha lives at lane (l4=0, l15=q); o rows are q=l4*4+r
        float alpha_o[4];
        #pragma unroll
        for (int r = 0; r < 4; ++r) alpha_o[r] = __shfl(alpha, l4 * 4 + r);
        #pragma unroll
        for (int df = 0; df < 8; ++df)
            #pragma unroll
            for (int r = 0; r < 4; ++r) o[df][r] *= alpha_o[r];

        // ---- P (already transposed in-lane) -> Pl, 4x ds_write_b64 ----
        #pragma unroll
        for (int kc = 0; kc < 4; ++kc) {
            bf16x4 pk;
            #pragma unroll
            for (int r = 0; r < 4; ++r) pk[r] = (__bf16)s[kc][r];
            *(bf16x4*)&Pl[w][l15][kc * 16 + l4 * 4] = pk;
        }

        // ---- O += P V (identical to proven R2 path) ----
        #pragma unroll
        for (int pc = 0; pc < 2; ++pc) {
            bf16x8 pa = *(const bf16x8*)&Pl[w][l15][pc * 32 + l4 * 8];
            #pragma unroll
            for (int df = 0; df < 8; ++df) {
                int cc  = df * 16 + l15;
                int kch = (pc * 4 + l4) ^ ((cc >> 3) & 7);
                bf16x8 vf = *(const bf16x8*)&Vt[cc][kch * 8];
                o[df] = __builtin_amdgcn_mfma_f32_16x16x32_bf16(pa, vf, o[df], 0, 0, 0);
            }
        }
    }

    if (!SPLIT || nch == 1) {
        float invl = 1.0f / lr;                 // valid for q = l15
        float inv_o[4];
        #pragma unroll
        for (int r = 0; r < 4; ++r) inv_o[r] = __shfl(invl, l4 * 4 + r);
        float* op = out + base;
        #pragma unroll
        for (int df = 0; df < 8; ++df)
            #pragma unroll
            for (int r = 0; r < 4; ++r) {
                int row = qb0 + w * 16 + l4 * 4 + r;
                op[(size_t)row * DIM + df * 16 + l15] = o[df][r] * inv_o[r];
            }
    } else {
        float* sp = part + (size_t)slot * SLOT_F32;
        if (l4 == 0) {                          // lanes 0..15 hold q = w*16+l15
            sp[w * 16 + l15]      = mr;
            sp[64 + w * 16 + l15] = lr;
        }
        #pragma unroll
        for (int df = 0; df < 8; ++df)
            #pragma unroll
            for (int r = 0; r < 4; ++r) {
                int rl = w * 16 + l4 * 4 + r;
                sp[128 + (size_t)rl * 128 + df * 16 + l15] = o[df][r];
            }
    }
}

// ---------------------------------------------------------------------------
// Kernel 3: combine partials for qt >= 8. Grid (56, B), 256 threads.
// m/l are in the exp2 domain -- weights use exp2f.
// ---------------------------------------------------------------------------
__global__ __launch_bounds__(256) void combine(
    const float* __restrict__ part, float* __restrict__ out)
{
    const int qt  = blockIdx.x + 8;
    const int b   = blockIdx.y;
    const int g   = qt >> 3;
    const int nch = g + 1;
    const int slot0 = b * TASKS_PER_B + 4 * g * (g + 1) + (qt & 7) * nch;

    const int t   = threadIdx.x;
    const int row = t >> 2;
    const int c0  = (t & 3) * 32;

    float M = -INFINITY;
    for (int c = 0; c < nch; ++c)
        M = fmaxf(M, part[(size_t)(slot0 + c) * SLOT_F32 + row]);
    float L = 0.f;
    for (int c = 0; c < nch; ++c) {
        const float* sp = part + (size_t)(slot0 + c) * SLOT_F32;
        L += sp[64 + row] * exp2f(sp[row] - M);
    }

    float4 acc[8];
    #pragma unroll
    for (int i = 0; i < 8; ++i) acc[i] = (float4){0.f, 0.f, 0.f, 0.f};
    for (int c = 0; c < nch; ++c) {
        const float* sp = part + (size_t)(slot0 + c) * SLOT_F32;
        float wgt = exp2f(sp[row] - M);
        const float* op = sp + 128 + (size_t)row * 128 + c0;
        #pragma unroll
        for (int i = 0; i < 8; ++i) {
            float4 f = *(const float4*)(op + i * 4);
            acc[i].x += wgt * f.x; acc[i].y += wgt * f.y;
            acc[i].z += wgt * f.z; acc[i].w += wgt * f.w;
        }
    }
    float invL = 1.0f / L;
    float* o = out + ((size_t)b * SEQ + (size_t)qt * 64 + row) * DIM + c0;
    #pragma unroll
    for (int i = 0; i < 8; ++i) {
        float4 f;
        f.x = acc[i].x * invL; f.y = acc[i].y * invL;
        f.z = acc[i].z * invL; f.w = acc[i].w * invL;
        *(float4*)(o + i * 4) = f;
    }
}

// ---------------------------------------------------------------------------
extern "C" void kernel_launch(void* const* d_in, const int* in_sizes, int n_in,
                              void* d_out, int out_size, void* d_ws, size_t ws_size,
                              hipStream_t stream) {
    const float* x  = (const float*)d_in[0];
    const float* Wq = (const float*)d_in[1];
    const float* Wk = (const float*)d_in[2];
    const float* Wv = (const float*)d_in[3];
    float* out = (float*)d_out;

    __bf16* qw = (__bf16*)d_ws;
    __bf16* kw = qw + (size_t)BATCH * SEQ * DIM;
    __bf16* vw = kw + (size_t)BATCH * SEQ * DIM;
    float*  part = (float*)((char*)d_ws + QKV_BYTES);

    qkv_proj<<<dim3(BATCH * SEQ / 128, 3), 256, 0, stream>>>(x, Wq, Wk, Wv, qw, kw, vw);

    if (ws_size >= QKV_BYTES + PART_BYTES) {
        attn<true><<<dim3(TASKS_PER_B, BATCH), 256, 0, stream>>>(qw, kw, vw, out, part);
        combine<<<dim3(56, BATCH), 256, 0, stream>>>(part, out);
    } else {
        attn<false><<<dim3(SEQ / 64, BATCH), 256, 0, stream>>>(qw, kw, vw, out, part);
    }
}